// Round 2
// baseline (2791.680 us; speedup 1.0000x reference)
//
#include <hip/hip_runtime.h>
#include <hip/hip_bf16.h>

#pragma clang fp contract(off)

#define TT 512
#define CC 256
#define TPAD 257
#define INFV 1e9f

__device__ __forceinline__ unsigned long long packkey(float v, unsigned c) {
  return ((unsigned long long)__float_as_uint(v) << 32) | (unsigned long long)c;
}

// ---------------- Phase 1: distance matrix + initial row-min keys ----------------
// Loads a 64-row tile of x, computes f64 norms, normalizes in LDS (f64 math,
// rounded once to f32 so stored xn ~= correctly-rounded truth).
__device__ void load_norm_tile(const float* __restrict__ xb, int rowBase,
                               float (*S)[TPAD], double* part, int tid) {
  for (int idx = tid; idx < 64 * CC; idx += 256) {
    int r = idx >> 8;
    int c = idx & (CC - 1);
    S[r][c] = xb[(size_t)(rowBase + r) * CC + c];
  }
  __syncthreads();
  {
    int r = tid >> 2, p = tid & 3;
    double s = 0.0;
    int c0 = p * 64;
    for (int c = 0; c < 64; ++c) {
      double v = (double)S[r][c0 + c];
      s = fma(v, v, s);
    }
    part[tid] = s;
  }
  __syncthreads();
  if ((tid & 3) == 0) {
    double tot = part[tid] + part[tid + 1] + part[tid + 2] + part[tid + 3];
    part[tid] = sqrt(tot) + 1e-8;  // norm + EPS, in f64
  }
  __syncthreads();
  for (int idx = tid; idx < 64 * CC; idx += 256) {
    int r = idx >> 8;
    int c = idx & (CC - 1);
    S[r][c] = (float)((double)S[r][c] / part[r << 2]);
  }
  __syncthreads();
}

__global__ __launch_bounds__(256) void build_dist_kernel(
    const float* __restrict__ x, float* __restrict__ dall,
    unsigned long long* __restrict__ rkall) {
  __shared__ float A[64][TPAD];
  __shared__ float Bs[64][TPAD];
  __shared__ double part[256];
  __shared__ unsigned long long rkl[64];

  int ta = blockIdx.x;   // row tile 0..7
  int b  = blockIdx.y;   // batch
  const float* xb = x + (size_t)b * TT * CC;
  float* d = dall + (size_t)b * TT * TT;
  int tid = threadIdx.x;
  if (tid < 64) rkl[tid] = ~0ull;
  load_norm_tile(xb, ta * 64, A, part, tid);

  int ty = tid & 15;   // col group (contiguous cols -> coalesced float4 stores)
  int tx = tid >> 4;   // row group
  for (int tb = 0; tb < 8; ++tb) {
    __syncthreads();   // previous Bs consumers done
    load_norm_tile(xb, tb * 64, Bs, part, tid);
    double acc[4][4];
#pragma unroll
    for (int ia = 0; ia < 4; ++ia)
#pragma unroll
      for (int ib = 0; ib < 4; ++ib) acc[ia][ib] = 0.0;
    for (int k = 0; k < CC; ++k) {
      double av[4], bv[4];
#pragma unroll
      for (int ia = 0; ia < 4; ++ia) av[ia] = (double)A[4 * tx + ia][k];
#pragma unroll
      for (int ib = 0; ib < 4; ++ib) bv[ib] = (double)Bs[4 * ty + ib][k];
#pragma unroll
      for (int ia = 0; ia < 4; ++ia)
#pragma unroll
        for (int ib = 0; ib < 4; ++ib)
          acc[ia][ib] = fma(av[ia], bv[ib], acc[ia][ib]);
    }
#pragma unroll
    for (int ia = 0; ia < 4; ++ia) {
      int gr = ta * 64 + 4 * tx + ia;
      int gcBase = tb * 64 + 4 * ty;
      float vt[4];
      unsigned long long key = ~0ull;
#pragma unroll
      for (int ib = 0; ib < 4; ++ib) {
        int gc = gcBase + ib;
        float v = (gr == gc) ? INFV : (float)(1.0 - acc[ia][ib]);
        vt[ib] = v;
        unsigned long long kk = packkey(v, (unsigned)gc);
        if (kk < key) key = kk;
      }
      *(float4*)(&d[(size_t)gr * TT + gcBase]) =
          make_float4(vt[0], vt[1], vt[2], vt[3]);
      // reduce row-min key across the 16 lanes sharing this row (lane bits 0..3)
#pragma unroll
      for (int off = 1; off < 16; off <<= 1) {
        unsigned long long o = __shfl_xor(key, off, 64);
        if (o < key) key = o;
      }
      if (ty == 0) atomicMin(&rkl[4 * tx + ia], key);
    }
  }
  __syncthreads();
  if (tid < 64) rkall[(size_t)b * TT + ta * 64 + tid] = rkl[tid];
}

// ---------------- Phase 2: sequential agglomerative merging, one wave/batch ----------------
__device__ __forceinline__ void recompute_row(const float* __restrict__ d,
                                              unsigned long long* rk, int r,
                                              int lane) {
  const float4* p = (const float4*)(d + (size_t)r * TT);
  float4 v0 = p[lane * 2];
  float4 v1 = p[lane * 2 + 1];
  int c0 = lane * 8;
  unsigned long long key = packkey(v0.x, c0);
  unsigned long long k;
  k = packkey(v0.y, c0 + 1); if (k < key) key = k;
  k = packkey(v0.z, c0 + 2); if (k < key) key = k;
  k = packkey(v0.w, c0 + 3); if (k < key) key = k;
  k = packkey(v1.x, c0 + 4); if (k < key) key = k;
  k = packkey(v1.y, c0 + 5); if (k < key) key = k;
  k = packkey(v1.z, c0 + 6); if (k < key) key = k;
  k = packkey(v1.w, c0 + 7); if (k < key) key = k;
#pragma unroll
  for (int off = 32; off >= 1; off >>= 1) {
    unsigned long long o = __shfl_xor(key, off, 64);
    if (o < key) key = o;
  }
  if (lane == 0) rk[r] = key;
}

__global__ __launch_bounds__(64) void agglom_kernel(
    const int* __restrict__ ncp, float* __restrict__ dall,
    const unsigned long long* __restrict__ rkall, int* __restrict__ outp) {
  __shared__ unsigned long long rk[TT];  // (valbits<<32)|first-min-col per row
  __shared__ float sizes[TT];
  __shared__ int assign[TT];
  __shared__ int rankArr[TT];
  int b = blockIdx.x;
  int lane = threadIdx.x;
  float* d = dall + (size_t)b * TT * TT;
#pragma unroll
  for (int u = 0; u < 8; ++u) {
    int r = u * 64 + lane;
    rk[r] = rkall[(size_t)b * TT + r];
    sizes[r] = 1.0f;
    assign[r] = r;
  }
  int K = ncp[0];
  if (K > TT) K = TT;
  if (K < 1) K = 1;
  int nm = TT - K;
  __threadfence_block();

  for (int iter = 0; iter < nm; ++iter) {
    // ---- global argmin: (val, row) lexicographic over cached row keys
    unsigned long long best = ~0ull;
#pragma unroll
    for (int u = 0; u < 8; ++u) {
      int r = u * 64 + lane;
      unsigned long long key =
          (rk[r] & 0xFFFFFFFF00000000ull) | (unsigned long long)(unsigned)r;
      if (key < best) best = key;
    }
#pragma unroll
    for (int off = 32; off >= 1; off >>= 1) {
      unsigned long long o = __shfl_xor(best, off, 64);
      if (o < best) best = o;
    }
    int i = (int)(best & 0xFFFFFFFFull);            // smaller index (row wins tie)
    int j = (int)(rk[i] & 0xFFFFFFFFull);           // its first-min column
    float ni = sizes[i], nj = sizes[j];
    float denom = ni + nj;

    // ---- newrow = (ni*d[i] + nj*d[j]) / (ni+nj), write row i, col i, col j
    float di[8], dj[8], nv[8];
#pragma unroll
    for (int u = 0; u < 8; ++u) {
      int r = u * 64 + lane;
      di[u] = d[(size_t)i * TT + r];
      dj[u] = d[(size_t)j * TT + r];
    }
    unsigned long long ikey = ~0ull;  // row i's new min, from registers
#pragma unroll
    for (int u = 0; u < 8; ++u) {
      int r = u * 64 + lane;
      float v = (ni * di[u] + nj * dj[u]) / denom;  // contract(off): mul,mul,add,div
      nv[u] = v;
      float w = (r == i || r == j) ? INFV : v;
      d[(size_t)i * TT + r] = w;       // row i (coalesced)
      d[(size_t)r * TT + i] = w;       // col i (scattered)
      d[(size_t)r * TT + j] = INFV;    // col j dies (scattered)
      unsigned long long kk = packkey(w, (unsigned)r);
      if (kk < ikey) ikey = kk;
    }
#pragma unroll
    for (int off = 32; off >= 1; off >>= 1) {
      unsigned long long o = __shfl_xor(ikey, off, 64);
      if (o < ikey) ikey = o;
    }

    // ---- lazy row-min maintenance + assign update
    unsigned fl = 0;
#pragma unroll
    for (int u = 0; u < 8; ++u) {
      int r = u * 64 + lane;
      if (r != i && r != j && sizes[r] > 0.0f) {
        unsigned long long cur = rk[r];
        unsigned c = (unsigned)(cur & 0xFFFFFFFFull);
        if (c == (unsigned)i || c == (unsigned)j) {
          fl |= (1u << u);             // cached min invalidated -> rescan
        } else {
          unsigned long long nk = packkey(nv[u], (unsigned)i);
          if (nk < cur) rk[r] = nk;    // handles equal-value, smaller-col too
        }
      }
      if (assign[r] == j) assign[r] = i;
    }
    if (lane == 0) {
      sizes[i] = denom;
      sizes[j] = 0.0f;
      rk[i] = ikey;
      rk[j] = packkey(INFV, 0xFFFFFFFFu);
    }
    __threadfence_block();   // matrix stores + LDS visible before rescans

    // ---- rescan invalidated rows (expected ~2/iter)
#pragma unroll
    for (int u = 0; u < 8; ++u) {
      unsigned long long m = __ballot((fl >> u) & 1);
      while (m) {
        int l2 = __ffsll((unsigned long long)m) - 1;
        m &= m - 1;
        recompute_row(d, rk, u * 64 + l2, lane);
      }
    }
    __threadfence_block();
  }

  // ---- canonical relabel: assign[t] == min original index of t's cluster,
  // so first = assign, is_first = (assign[r]==r), rank = prefix-sum
  int isf[8];
  int cnt = 0;
#pragma unroll
  for (int t = 0; t < 8; ++t) {
    int r = lane * 8 + t;
    isf[t] = (assign[r] == r) ? 1 : 0;
    cnt += isf[t];
  }
  int incl = cnt;
#pragma unroll
  for (int off = 1; off < 64; off <<= 1) {
    int o = __shfl_up(incl, (unsigned)off, 64);
    if (lane >= off) incl += o;
  }
  int base = incl - cnt;
#pragma unroll
  for (int t = 0; t < 8; ++t) {
    int r = lane * 8 + t;
    if (isf[t]) rankArr[r] = base++;
  }
  __threadfence_block();
#pragma unroll
  for (int u = 0; u < 8; ++u) {
    int r = u * 64 + lane;
    outp[(size_t)b * TT + r] = rankArr[assign[r]];
  }
}

extern "C" void kernel_launch(void* const* d_in, const int* in_sizes, int n_in,
                              void* d_out, int out_size, void* d_ws, size_t ws_size,
                              hipStream_t stream) {
  const float* x = (const float*)d_in[0];
  const int* ncp = (const int*)d_in[1];
  int B = in_sizes[0] / (TT * CC);
  float* dall = (float*)d_ws;                                   // B * 512*512 f32 (64 MiB)
  unsigned long long* rkall =
      (unsigned long long*)((char*)d_ws + (size_t)B * TT * TT * sizeof(float));
  int* outp = (int*)d_out;

  dim3 g1(TT / 64, B);
  build_dist_kernel<<<g1, 256, 0, stream>>>(x, dall, rkall);
  agglom_kernel<<<B, 64, 0, stream>>>(ncp, dall, rkall, outp);
}